// Round 2
// baseline (1044.807 us; speedup 1.0000x reference)
//
#include <hip/hip_runtime.h>
#include <stdint.h>

typedef unsigned short u16;
typedef short bf16x8 __attribute__((ext_vector_type(8)));
typedef float f32x4 __attribute__((ext_vector_type(4)));

__device__ __forceinline__ float b2f(u16 u){
  unsigned int i = ((unsigned int)u) << 16;
  return __builtin_bit_cast(float, i);
}
__device__ __forceinline__ u16 f2b(float f){
  unsigned int i = __builtin_bit_cast(unsigned int, f);
  i += 0x7FFFu + ((i >> 16) & 1u);   // round-nearest-even
  return (u16)(i >> 16);
}

__device__ __forceinline__ void async16(const void* g, void* l){
  __builtin_amdgcn_global_load_lds((__attribute__((address_space(1))) void*)(void*)g,
                                   (__attribute__((address_space(3))) void*)l, 16, 0, 0);
}

// ---------------- dtype probe: flag=1 if external tensors are fp32 ----------------
// q_w ~ N(0,1/768): as bf16, exponent field <= ~125. As fp32-read-as-u16, half the
// u16s are mantissa low-halves (uniform) -> ~45% have exp>=140. Count over 4096.
__global__ void probe_kernel(const u16* __restrict__ qw, int* __restrict__ flag){
  if (threadIdx.x == 0){
    int cnt = 0;
    for (int i = 0; i < 4096; ++i){
      int e = (qw[i] >> 7) & 0xFF;
      cnt += (e >= 140);
    }
    *flag = (cnt > 64) ? 1 : 0;
  }
}

// ---------------- top-k: rank-by-counting, tie-break lower index ----------------
__global__ __launch_bounds__(576) void topk_kernel(const void* __restrict__ aa,
                                                   int* __restrict__ qrows,
                                                   const int* __restrict__ flagp){
  const int b = blockIdx.x;
  const int isf32 = *flagp;
  __shared__ float vals[576];
  const int i = threadIdx.x;           // 0..575
  const size_t off = (size_t)b*332929 + 1 + i;   // 577*577 = 332929
  vals[i] = isf32 ? ((const float*)aa)[off] : b2f(((const u16*)aa)[off]);
  __syncthreads();
  const float vi = vals[i];
  int rank = 0;
  for (int j = 0; j < 576; ++j){
    float vj = vals[j];
    rank += (int)((vj > vi) || (vj == vi && j < i));
  }
  if (rank < 57) qrows[b*58 + 1 + rank] = b*577 + i + 1;
  if (i == 0)    qrows[b*58] = b*577;
}

// ---------------- GEMM: C[m][n] = sum_k A[m][k] * W[n][k]  (K=N=768) ----------------
// 128x128 tile, BK=32, 4 waves (2x2), 4x4 16x16x32 MFMA per wave.
// aExt: A is an external input (dtype per flag). W always external. cOut: C is d_out.
// vt_mode==1: store transposed into Vt[b][h][d][n] with n-stride 608 (always bf16).
__global__ __launch_bounds__(256) void gemm_bt(
    const void* __restrict__ A, const void* __restrict__ W,
    void* __restrict__ C, int M,
    const int* __restrict__ gatherA, const int* __restrict__ scatterC,
    const void* __restrict__ bias, int vt_mode, int aExt, int cOut,
    const int* __restrict__ flagp)
{
  __shared__ __align__(16) u16 As[128*32];
  __shared__ __align__(16) u16 Bs[128*32];
  const int flag = *flagp;
  const int aF32 = flag & aExt;
  const int tid = threadIdx.x;
  const int w = tid >> 6, l = tid & 63;
  const int mBase = blockIdx.y * 128;
  const int nBase = blockIdx.x * 128;

  const int r0 = tid >> 2;
  const int kc = (tid & 3) * 8;
  int arow0 = mBase + r0;       if (arow0 > M-1) arow0 = M-1;
  int arow1 = mBase + 64 + r0;  if (arow1 > M-1) arow1 = M-1;
  if (gatherA){ arow0 = gatherA[arow0]; arow1 = gatherA[arow1]; }
  const size_t aoff0 = (size_t)arow0 * 768 + kc;
  const size_t aoff1 = (size_t)arow1 * 768 + kc;
  const size_t boff0 = (size_t)(nBase + r0) * 768 + kc;
  const size_t boff1 = (size_t)(nBase + 64 + r0) * 768 + kc;
  u16* as0 = &As[tid * 8];
  u16* as1 = &As[(256 + tid) * 8];
  u16* bs0 = &Bs[tid * 8];
  u16* bs1 = &Bs[(256 + tid) * 8];

  f32x4 acc[4][4] = {};
  const int wm = (w >> 1) * 64, wn = (w & 1) * 64;
  const int lm = l & 15, lk = (l >> 4) * 8;

  const u16* A16 = (const u16*)A; const float* A32 = (const float*)A;
  const u16* W16 = (const u16*)W; const float* W32 = (const float*)W;

  for (int k0 = 0; k0 < 768; k0 += 32){
    if (!flag){
      // everything bf16: async direct-to-LDS
      async16(A16 + aoff0 + k0, as0);
      async16(A16 + aoff1 + k0, as1);
      async16(W16 + boff0 + k0, bs0);
      async16(W16 + boff1 + k0, bs1);
    } else {
      // W (and maybe A) fp32: load + convert + ds_write
      bf16x8 v;
      if (aF32){
        f32x4 f0 = *(const f32x4*)(A32 + aoff0 + k0);
        f32x4 f1 = *(const f32x4*)(A32 + aoff0 + k0 + 4);
#pragma unroll
        for (int j = 0; j < 4; ++j){ v[j] = (short)f2b(f0[j]); v[4+j] = (short)f2b(f1[j]); }
        *(bf16x8*)as0 = v;
        f0 = *(const f32x4*)(A32 + aoff1 + k0);
        f1 = *(const f32x4*)(A32 + aoff1 + k0 + 4);
#pragma unroll
        for (int j = 0; j < 4; ++j){ v[j] = (short)f2b(f0[j]); v[4+j] = (short)f2b(f1[j]); }
        *(bf16x8*)as1 = v;
      } else {
        *(bf16x8*)as0 = *(const bf16x8*)(A16 + aoff0 + k0);
        *(bf16x8*)as1 = *(const bf16x8*)(A16 + aoff1 + k0);
      }
      f32x4 g0 = *(const f32x4*)(W32 + boff0 + k0);
      f32x4 g1 = *(const f32x4*)(W32 + boff0 + k0 + 4);
#pragma unroll
      for (int j = 0; j < 4; ++j){ v[j] = (short)f2b(g0[j]); v[4+j] = (short)f2b(g1[j]); }
      *(bf16x8*)bs0 = v;
      g0 = *(const f32x4*)(W32 + boff1 + k0);
      g1 = *(const f32x4*)(W32 + boff1 + k0 + 4);
#pragma unroll
      for (int j = 0; j < 4; ++j){ v[j] = (short)f2b(g0[j]); v[4+j] = (short)f2b(g1[j]); }
      *(bf16x8*)bs1 = v;
    }
    __syncthreads();
    bf16x8 af[4], bfr[4];
#pragma unroll
    for (int i = 0; i < 4; ++i) af[i]  = *(const bf16x8*)&As[(wm + i*16 + lm)*32 + lk];
#pragma unroll
    for (int j = 0; j < 4; ++j) bfr[j] = *(const bf16x8*)&Bs[(wn + j*16 + lm)*32 + lk];
#pragma unroll
    for (int i = 0; i < 4; ++i)
#pragma unroll
      for (int j = 0; j < 4; ++j)
        acc[i][j] = __builtin_amdgcn_mfma_f32_16x16x32_bf16(af[i], bfr[j], acc[i][j], 0, 0, 0);
    __syncthreads();
  }

  // epilogue: C layout col=lane&15, row=(lane>>4)*4+reg
  if (vt_mode == 0){
    const int cF32 = flag & cOut;
#pragma unroll
    for (int i = 0; i < 4; ++i){
#pragma unroll
      for (int r = 0; r < 4; ++r){
        int m = mBase + wm + i*16 + ((l >> 4) << 2) + r;
        if (m < M){
          int orow = scatterC ? scatterC[m] : m;
          size_t base = (size_t)orow * 768;
#pragma unroll
          for (int j = 0; j < 4; ++j){
            int n = nBase + wn + j*16 + lm;
            float v = acc[i][j][r];
            if (bias) v += flag ? ((const float*)bias)[n] : b2f(((const u16*)bias)[n]);
            if (cF32) ((float*)C)[base + n] = v;
            else      ((u16*)C)[base + n] = f2b(v);
          }
        }
      }
    }
  } else {
#pragma unroll
    for (int i = 0; i < 4; ++i){
#pragma unroll
      for (int r = 0; r < 4; ++r){
        int m = mBase + wm + i*16 + ((l >> 4) << 2) + r;
        if (m < M){
          int bb = m / 577;
          int nn = m - bb*577;
#pragma unroll
          for (int j = 0; j < 4; ++j){
            int nf = nBase + wn + j*16 + lm;        // feature = h*64+d
            ((u16*)C)[((size_t)(bb*12 + (nf >> 6))*64 + (nf & 63))*608 + nn] = f2b(acc[i][j][r]);
          }
        }
      }
    }
  }
}

// ---------------- attention: per (m-tile of 16, h, b); exact two-pass softmax ----------------
#define SLD 612   // score LDS row stride (608 data cols + 4 pad)
__global__ __launch_bounds__(256) void attn_kernel(
    const u16* __restrict__ lq, const u16* __restrict__ K,
    const u16* __restrict__ Vt, u16* __restrict__ lout)
{
  const int mt = blockIdx.x, h = blockIdx.y, b = blockIdx.z;
  __shared__ __align__(16) u16 qs[16*64];
  __shared__ __align__(16) float S[16*SLD];
  __shared__ float red[16*17];
  const int tid = threadIdx.x, w = tid >> 6, l = tid & 63;
  const int lm = l & 15, lk = (l >> 4) * 8;

  for (int idx = tid; idx < 1024; idx += 256){
    int r = idx >> 6, c = idx & 63;
    int gm = mt*16 + r;
    qs[idx] = (gm < 58) ? lq[((size_t)b*58 + gm)*768 + h*64 + c] : (u16)0;
  }
  __syncthreads();
  bf16x8 aq0 = *(const bf16x8*)&qs[lm*64 + lk];
  bf16x8 aq1 = *(const bf16x8*)&qs[lm*64 + 32 + lk];

  // scores: S[m][n] = (Q·K^T)*0.125, n padded to 608
  const u16* Kb = K + (size_t)b*577*768 + h*64;
  for (int t = w; t < 38; t += 4){
    int n0 = t*16;
    int n = n0 + lm; if (n > 576) n = 576;
    const u16* kp = Kb + (size_t)n*768;
    bf16x8 b0 = *(const bf16x8*)&kp[lk];
    bf16x8 b1 = *(const bf16x8*)&kp[32 + lk];
    f32x4 c = {};
    c = __builtin_amdgcn_mfma_f32_16x16x32_bf16(aq0, b0, c, 0, 0, 0);
    c = __builtin_amdgcn_mfma_f32_16x16x32_bf16(aq1, b1, c, 0, 0, 0);
#pragma unroll
    for (int r = 0; r < 4; ++r)
      S[(((l >> 4) << 2) + r)*SLD + n0 + lm] = c[r] * 0.125f;
  }
  __syncthreads();

  // softmax over n<577, 16 threads per row
  const int row = tid >> 4, g = tid & 15;
  float mx = -1e30f;
  for (int n = g; n < 577; n += 16) mx = fmaxf(mx, S[row*SLD + n]);
  red[row*17 + g] = mx;
  __syncthreads();
  float m2 = red[row*17];
#pragma unroll
  for (int i = 1; i < 16; ++i) m2 = fmaxf(m2, red[row*17 + i]);
  float sum = 0.f;
  for (int n = g; n < 577; n += 16){
    float e = __expf(S[row*SLD + n] - m2);
    S[row*SLD + n] = e;
    sum += e;
  }
  __syncthreads();
  red[row*17 + g] = sum;
  __syncthreads();
  float s2 = 0.f;
#pragma unroll
  for (int i = 0; i < 16; ++i) s2 += red[row*17 + i];
  float inv = 1.f / s2;
  for (int n = g; n < 577; n += 16) S[row*SLD + n] *= inv;
  for (int n = 577 + g; n < 608; n += 16) S[row*SLD + n] = 0.f;
  __syncthreads();

  // O = P · V via Vt[b][h][d][n]; wave w owns d-tile w
  const u16* Vb = Vt + ((size_t)(b*12 + h) * 64) * 608;
  f32x4 oc = {};
  for (int ks = 0; ks < 19; ++ks){
    int kb = ks*32 + lk;
    f32x4 p0 = *(const f32x4*)&S[lm*SLD + kb];
    f32x4 p1 = *(const f32x4*)&S[lm*SLD + kb + 4];
    bf16x8 af;
#pragma unroll
    for (int j = 0; j < 4; ++j){ af[j] = (short)f2b(p0[j]); af[4+j] = (short)f2b(p1[j]); }
    bf16x8 bv = *(const bf16x8*)&Vb[(size_t)(w*16 + lm)*608 + kb];
    oc = __builtin_amdgcn_mfma_f32_16x16x32_bf16(af, bv, oc, 0, 0, 0);
  }
#pragma unroll
  for (int r = 0; r < 4; ++r){
    int ml = mt*16 + ((l >> 4) << 2) + r;
    if (ml < 58)
      lout[((size_t)b*58 + ml)*768 + h*64 + w*16 + lm] = f2b(oc[r]);
  }
}

// ---------------- launch ----------------
extern "C" void kernel_launch(void* const* d_in, const int* in_sizes, int n_in,
                              void* d_out, int out_size, void* d_ws, size_t ws_size,
                              hipStream_t stream)
{
  const void* x    = d_in[0];
  const void* aacc = d_in[1];
  const void* q_w  = d_in[2];
  const void* k_w  = d_in[3];
  const void* v_w  = d_in[4];
  const void* p_w  = d_in[5];
  const void* p_b  = d_in[6];

  const int M  = 36928;   // 64*577
  const int Ms = 3712;    // 64*58
  u16* Kbuf = (u16*)d_ws;                              // 36928*768
  u16* Vt   = Kbuf + (size_t)M * 768;                  // 768*64*608 (b*12+h, d, n)
  u16* lq   = Vt + (size_t)768 * 64 * 608;             // 3712*768
  u16* lout = lq + (size_t)Ms * 768;                   // 3712*768
  int* qrows = (int*)(lout + (size_t)Ms * 768);        // 3712 ints
  int* flagp = qrows + 3712;

  probe_kernel<<<1, 64, 0, stream>>>((const u16*)q_w, flagp);
  topk_kernel<<<64, 576, 0, stream>>>(aacc, qrows, flagp);
  // K = x @ k_w^T
  gemm_bt<<<dim3(6, 289), 256, 0, stream>>>(x, k_w, Kbuf, M, nullptr, nullptr, nullptr, 0, 1, 0, flagp);
  // Vt = transpose-per-head of x @ v_w^T
  gemm_bt<<<dim3(6, 289), 256, 0, stream>>>(x, v_w, Vt, M, nullptr, nullptr, nullptr, 1, 1, 0, flagp);
  // local_q = x[sel rows] @ q_w^T   (3712 = 29*128 exact)
  gemm_bt<<<dim3(6, 29), 256, 0, stream>>>(x, q_w, lq, Ms, qrows, nullptr, nullptr, 0, 1, 0, flagp);
  // attention -> local_out
  attn_kernel<<<dim3(4, 12, 64), 256, 0, stream>>>(lq, Kbuf, Vt, lout);
  // out = x @ proj_w^T + b  (all rows)
  gemm_bt<<<dim3(6, 289), 256, 0, stream>>>(x, p_w, d_out, M, nullptr, nullptr, p_b, 0, 1, 1, flagp);
  // overwrite selected rows: out[qrows] = local_out @ proj_w^T + b
  gemm_bt<<<dim3(6, 29), 256, 0, stream>>>(lout, p_w, d_out, Ms, nullptr, qrows, p_b, 0, 0, 1, flagp);
}

// Round 3
// 830.107 us; speedup vs baseline: 1.2586x; 1.2586x over previous
//
#include <hip/hip_runtime.h>
#include <stdint.h>

typedef unsigned short u16;
typedef short bf16x8 __attribute__((ext_vector_type(8)));
typedef float f32x4 __attribute__((ext_vector_type(4)));

__device__ __forceinline__ float b2f(u16 u){
  unsigned int i = ((unsigned int)u) << 16;
  return __builtin_bit_cast(float, i);
}
__device__ __forceinline__ u16 f2b(float f){
  unsigned int i = __builtin_bit_cast(unsigned int, f);
  i += 0x7FFFu + ((i >> 16) & 1u);   // round-nearest-even
  return (u16)(i >> 16);
}

__device__ __forceinline__ void async16(const void* g, void* l){
  __builtin_amdgcn_global_load_lds((__attribute__((address_space(1))) void*)(void*)g,
                                   (__attribute__((address_space(3))) void*)l, 16, 0, 0);
}

// ---------------- dtype probe: flag=1 if external tensors are fp32 ----------------
__global__ void probe_kernel(const u16* __restrict__ qw, int* __restrict__ flag){
  if (threadIdx.x == 0){
    int cnt = 0;
    for (int i = 0; i < 4096; ++i){
      int e = (qw[i] >> 7) & 0xFF;
      cnt += (e >= 140);
    }
    *flag = (cnt > 64) ? 1 : 0;
  }
}

// ---------------- convert external tensor -> bf16 (8 elems/thread) ----------------
__global__ __launch_bounds__(256) void cvt_kernel(const void* __restrict__ src,
                                                  u16* __restrict__ dst, int n,
                                                  const int* __restrict__ flagp){
  const int i = (blockIdx.x * 256 + threadIdx.x) * 8;
  if (i >= n) return;
  if (*flagp){
    f32x4 a = *(const f32x4*)((const float*)src + i);
    f32x4 b = *(const f32x4*)((const float*)src + i + 4);
    bf16x8 v;
#pragma unroll
    for (int j = 0; j < 4; ++j){ v[j] = (short)f2b(a[j]); v[4+j] = (short)f2b(b[j]); }
    *(bf16x8*)(dst + i) = v;
  } else {
    *(bf16x8*)(dst + i) = *(const bf16x8*)((const u16*)src + i);
  }
}

// bias -> fp32
__global__ void cvtb_kernel(const void* __restrict__ src, float* __restrict__ dst,
                            int n, const int* __restrict__ flagp){
  int i = blockIdx.x * 256 + threadIdx.x;
  if (i < n) dst[i] = *flagp ? ((const float*)src)[i] : b2f(((const u16*)src)[i]);
}

// ---------------- top-k: rank-by-counting, tie-break lower index ----------------
__global__ __launch_bounds__(576) void topk_kernel(const void* __restrict__ aa,
                                                   int* __restrict__ qrows,
                                                   const int* __restrict__ flagp){
  const int b = blockIdx.x;
  const int isf32 = *flagp;
  __shared__ float vals[576];
  const int i = threadIdx.x;           // 0..575
  const size_t off = (size_t)b*332929 + 1 + i;   // 577*577 = 332929
  vals[i] = isf32 ? ((const float*)aa)[off] : b2f(((const u16*)aa)[off]);
  __syncthreads();
  const float vi = vals[i];
  int rank = 0;
  for (int j = 0; j < 576; ++j){
    float vj = vals[j];
    rank += (int)((vj > vi) || (vj == vi && j < i));
  }
  if (rank < 57) qrows[b*58 + 1 + rank] = b*577 + i + 1;
  if (i == 0)    qrows[b*58] = b*577;
}

// ---------------- GEMM: C[m][n] = sum_k A[m][k] * W[n][k]  (K=N=768, bf16 in) ----------------
// 128x128 tile, BK=32, 4 waves (2x2), 4x4 16x16x32 MFMA, global_load_lds w=16.
// cmode: 0 = bf16 C, 1 = Vt transposed bf16 (stride 608), 2 = fp32 C (+bias)
__global__ __launch_bounds__(256) void gemm_bt(
    const u16* __restrict__ A, const u16* __restrict__ W,
    void* __restrict__ C, int M,
    const int* __restrict__ gatherA, const int* __restrict__ scatterC,
    const float* __restrict__ bias, int cmode)
{
  __shared__ __align__(16) u16 As[128*32];
  __shared__ __align__(16) u16 Bs[128*32];
  const int tid = threadIdx.x;
  const int w = tid >> 6, l = tid & 63;
  const int mBase = blockIdx.y * 128;
  const int nBase = blockIdx.x * 128;

  const int r0 = tid >> 2;
  const int kc = (tid & 3) * 8;
  int arow0 = mBase + r0;       if (arow0 > M-1) arow0 = M-1;
  int arow1 = mBase + 64 + r0;  if (arow1 > M-1) arow1 = M-1;
  if (gatherA){ arow0 = gatherA[arow0]; arow1 = gatherA[arow1]; }
  const u16* ag0 = A + (size_t)arow0 * 768 + kc;
  const u16* ag1 = A + (size_t)arow1 * 768 + kc;
  const u16* bg0 = W + (size_t)(nBase + r0) * 768 + kc;
  const u16* bg1 = W + (size_t)(nBase + 64 + r0) * 768 + kc;
  u16* as0 = &As[tid * 8];
  u16* as1 = &As[(256 + tid) * 8];
  u16* bs0 = &Bs[tid * 8];
  u16* bs1 = &Bs[(256 + tid) * 8];

  f32x4 acc[4][4] = {};
  const int wm = (w >> 1) * 64, wn = (w & 1) * 64;
  const int lm = l & 15, lk = (l >> 4) * 8;

  for (int k0 = 0; k0 < 768; k0 += 32){
    async16(ag0 + k0, as0);
    async16(ag1 + k0, as1);
    async16(bg0 + k0, bs0);
    async16(bg1 + k0, bs1);
    __syncthreads();
    bf16x8 af[4], bfr[4];
#pragma unroll
    for (int i = 0; i < 4; ++i) af[i]  = *(const bf16x8*)&As[(wm + i*16 + lm)*32 + lk];
#pragma unroll
    for (int j = 0; j < 4; ++j) bfr[j] = *(const bf16x8*)&Bs[(wn + j*16 + lm)*32 + lk];
#pragma unroll
    for (int i = 0; i < 4; ++i)
#pragma unroll
      for (int j = 0; j < 4; ++j)
        acc[i][j] = __builtin_amdgcn_mfma_f32_16x16x32_bf16(af[i], bfr[j], acc[i][j], 0, 0, 0);
    __syncthreads();
  }

  // epilogue: C layout col=lane&15, row=(lane>>4)*4+reg
  if (cmode == 1){
#pragma unroll
    for (int i = 0; i < 4; ++i){
#pragma unroll
      for (int r = 0; r < 4; ++r){
        int m = mBase + wm + i*16 + ((l >> 4) << 2) + r;
        if (m < M){
          int bb = m / 577;
          int nn = m - bb*577;
#pragma unroll
          for (int j = 0; j < 4; ++j){
            int nf = nBase + wn + j*16 + lm;        // feature = h*64+d
            ((u16*)C)[((size_t)(bb*12 + (nf >> 6))*64 + (nf & 63))*608 + nn] = f2b(acc[i][j][r]);
          }
        }
      }
    }
  } else {
#pragma unroll
    for (int i = 0; i < 4; ++i){
#pragma unroll
      for (int r = 0; r < 4; ++r){
        int m = mBase + wm + i*16 + ((l >> 4) << 2) + r;
        if (m < M){
          int orow = scatterC ? scatterC[m] : m;
          size_t base = (size_t)orow * 768;
#pragma unroll
          for (int j = 0; j < 4; ++j){
            int n = nBase + wn + j*16 + lm;
            float v = acc[i][j][r];
            if (bias) v += bias[n];
            if (cmode == 2) ((float*)C)[base + n] = v;
            else            ((u16*)C)[base + n] = f2b(v);
          }
        }
      }
    }
  }
}

// ---------------- attention: per (m-tile of 16, h, b); exact two-pass softmax ----------------
#define SLD 612   // score LDS row stride (608 data cols + 4 pad)
__global__ __launch_bounds__(256) void attn_kernel(
    const u16* __restrict__ lq, const u16* __restrict__ K,
    const u16* __restrict__ Vt, u16* __restrict__ lout)
{
  const int mt = blockIdx.x, h = blockIdx.y, b = blockIdx.z;
  __shared__ __align__(16) u16 qs[16*64];
  __shared__ __align__(16) float S[16*SLD];
  __shared__ float red[16*17];
  const int tid = threadIdx.x, w = tid >> 6, l = tid & 63;
  const int lm = l & 15, lk = (l >> 4) * 8;

  for (int idx = tid; idx < 1024; idx += 256){
    int r = idx >> 6, c = idx & 63;
    int gm = mt*16 + r;
    qs[idx] = (gm < 58) ? lq[((size_t)b*58 + gm)*768 + h*64 + c] : (u16)0;
  }
  __syncthreads();
  bf16x8 aq0 = *(const bf16x8*)&qs[lm*64 + lk];
  bf16x8 aq1 = *(const bf16x8*)&qs[lm*64 + 32 + lk];

  // scores: S[m][n] = (Q·K^T)*0.125, n padded to 608
  const u16* Kb = K + (size_t)b*577*768 + h*64;
  for (int t = w; t < 38; t += 4){
    int n0 = t*16;
    int n = n0 + lm; if (n > 576) n = 576;
    const u16* kp = Kb + (size_t)n*768;
    bf16x8 b0 = *(const bf16x8*)&kp[lk];
    bf16x8 b1 = *(const bf16x8*)&kp[32 + lk];
    f32x4 c = {};
    c = __builtin_amdgcn_mfma_f32_16x16x32_bf16(aq0, b0, c, 0, 0, 0);
    c = __builtin_amdgcn_mfma_f32_16x16x32_bf16(aq1, b1, c, 0, 0, 0);
#pragma unroll
    for (int r = 0; r < 4; ++r)
      S[(((l >> 4) << 2) + r)*SLD + n0 + lm] = c[r] * 0.125f;
  }
  __syncthreads();

  // softmax over n<577, 16 threads per row
  const int row = tid >> 4, g = tid & 15;
  float mx = -1e30f;
  for (int n = g; n < 577; n += 16) mx = fmaxf(mx, S[row*SLD + n]);
  red[row*17 + g] = mx;
  __syncthreads();
  float m2 = red[row*17];
#pragma unroll
  for (int i = 1; i < 16; ++i) m2 = fmaxf(m2, red[row*17 + i]);
  float sum = 0.f;
  for (int n = g; n < 577; n += 16){
    float e = __expf(S[row*SLD + n] - m2);
    S[row*SLD + n] = e;
    sum += e;
  }
  __syncthreads();
  red[row*17 + g] = sum;
  __syncthreads();
  float s2 = 0.f;
#pragma unroll
  for (int i = 0; i < 16; ++i) s2 += red[row*17 + i];
  float inv = 1.f / s2;
  for (int n = g; n < 577; n += 16) S[row*SLD + n] *= inv;
  for (int n = 577 + g; n < 608; n += 16) S[row*SLD + n] = 0.f;
  __syncthreads();

  // O = P · V via Vt[b][h][d][n]; wave w owns d-tile w
  const u16* Vb = Vt + ((size_t)(b*12 + h) * 64) * 608;
  f32x4 oc = {};
  for (int ks = 0; ks < 19; ++ks){
    int kb = ks*32 + lk;
    f32x4 p0 = *(const f32x4*)&S[lm*SLD + kb];
    f32x4 p1 = *(const f32x4*)&S[lm*SLD + kb + 4];
    bf16x8 af;
#pragma unroll
    for (int j = 0; j < 4; ++j){ af[j] = (short)f2b(p0[j]); af[4+j] = (short)f2b(p1[j]); }
    bf16x8 bv = *(const bf16x8*)&Vb[(size_t)(w*16 + lm)*608 + kb];
    oc = __builtin_amdgcn_mfma_f32_16x16x32_bf16(af, bv, oc, 0, 0, 0);
  }
#pragma unroll
  for (int r = 0; r < 4; ++r){
    int ml = mt*16 + ((l >> 4) << 2) + r;
    if (ml < 58)
      lout[((size_t)b*58 + ml)*768 + h*64 + w*16 + lm] = f2b(oc[r]);
  }
}

// ---------------- launch ----------------
extern "C" void kernel_launch(void* const* d_in, const int* in_sizes, int n_in,
                              void* d_out, int out_size, void* d_ws, size_t ws_size,
                              hipStream_t stream)
{
  const void* x    = d_in[0];
  const void* aacc = d_in[1];
  const void* q_w  = d_in[2];
  const void* k_w  = d_in[3];
  const void* v_w  = d_in[4];
  const void* p_w  = d_in[5];
  const void* p_b  = d_in[6];

  const int M  = 36928;   // 64*577
  const int Ms = 3712;    // 64*58
  const int XE = M * 768;       // 28,360,704
  const int WE = 768 * 768;     // 589,824

  u16* Kbuf = (u16*)d_ws;                              // 36928*768
  u16* Vt   = Kbuf + (size_t)M * 768;                  // 768*64*608 (b*12+h, d, n)
  u16* lq   = Vt + (size_t)768 * 64 * 608;             // 3712*768
  u16* lout = lq + (size_t)Ms * 768;                   // 3712*768
  u16* xb   = lout + (size_t)Ms * 768;                 // 36928*768 bf16 x
  u16* qwb  = xb + (size_t)XE;                         // 4 weights bf16
  u16* kwb  = qwb + WE;
  u16* vwb  = kwb + WE;
  u16* pwb  = vwb + WE;
  float* biasf = (float*)(pwb + WE);                   // 768 fp32
  int* qrows = (int*)(biasf + 768);                    // 3712 ints
  int* flagp = qrows + 3712;

  probe_kernel<<<1, 64, 0, stream>>>((const u16*)q_w, flagp);
  cvt_kernel<<<XE/8/256, 256, 0, stream>>>(x, xb, XE, flagp);
  cvt_kernel<<<WE/8/256, 256, 0, stream>>>(q_w, qwb, WE, flagp);
  cvt_kernel<<<WE/8/256, 256, 0, stream>>>(k_w, kwb, WE, flagp);
  cvt_kernel<<<WE/8/256, 256, 0, stream>>>(v_w, vwb, WE, flagp);
  cvt_kernel<<<WE/8/256, 256, 0, stream>>>(p_w, pwb, WE, flagp);
  cvtb_kernel<<<3, 256, 0, stream>>>(p_b, biasf, 768, flagp);
  topk_kernel<<<64, 576, 0, stream>>>(aacc, qrows, flagp);

  // K = x @ k_w^T
  gemm_bt<<<dim3(6, 289), 256, 0, stream>>>(xb, kwb, Kbuf, M, nullptr, nullptr, nullptr, 0);
  // Vt = transpose-per-head of x @ v_w^T
  gemm_bt<<<dim3(6, 289), 256, 0, stream>>>(xb, vwb, Vt, M, nullptr, nullptr, nullptr, 1);
  // local_q = x[sel rows] @ q_w^T   (3712 = 29*128 exact)
  gemm_bt<<<dim3(6, 29), 256, 0, stream>>>(xb, qwb, lq, Ms, qrows, nullptr, nullptr, 0);
  // attention -> local_out
  attn_kernel<<<dim3(4, 12, 64), 256, 0, stream>>>(lq, Kbuf, Vt, lout);
  // out = x @ proj_w^T + b  (all rows, fp32 out)
  gemm_bt<<<dim3(6, 289), 256, 0, stream>>>(xb, pwb, d_out, M, nullptr, nullptr, biasf, 2);
  // overwrite selected rows: out[qrows] = local_out @ proj_w^T + b
  gemm_bt<<<dim3(6, 29), 256, 0, stream>>>(lout, pwb, d_out, Ms, nullptr, qrows, biasf, 2);
}